// Round 4
// baseline (339.009 us; speedup 1.0000x reference)
//
#include <hip/hip_runtime.h>
#include <stdint.h>

typedef __attribute__((ext_vector_type(8))) short short8;
typedef __attribute__((ext_vector_type(4))) float f32x4;
typedef __attribute__((ext_vector_type(16))) float f32x16;
typedef __attribute__((ext_vector_type(4))) int i32x4;

#define B_ 8
#define C_ 64
#define N_ 4096

__device__ __forceinline__ unsigned short f2bf(float f) {
  unsigned int u = __float_as_uint(f);
  u = (u + 0x7fffu + ((u >> 16) & 1u)) >> 16;
  return (unsigned short)u;
}
__device__ __forceinline__ int pk2(float lo, float hi2) {
  return (int)((unsigned)f2bf(lo) | ((unsigned)f2bf(hi2) << 16));
}

// ---------------- QKV projection (verified rounds 1-2) ----------------
__global__ __launch_bounds__(256) void qkv_proj(
    const float* __restrict__ x,
    const float* __restrict__ Wq, const float* __restrict__ bq,
    const float* __restrict__ Wk, const float* __restrict__ bk,
    const float* __restrict__ Wv, const float* __restrict__ bv,
    unsigned short* __restrict__ qo, unsigned short* __restrict__ ko,
    unsigned short* __restrict__ vto) {
  const int n = blockIdx.x * 256 + threadIdx.x;
  const int m = blockIdx.y;  // 0=q, 1=k, 2=v(transposed)
  const int b = blockIdx.z;
  const float* W = (m == 0) ? Wq : (m == 1) ? Wk : Wv;
  const float* bi = (m == 0) ? bq : (m == 1) ? bk : bv;

  float xv[64];
  const float* xp = x + (size_t)b * C_ * N_ + n;
#pragma unroll
  for (int c = 0; c < 64; ++c) xv[c] = xp[(size_t)c * N_];

  if (m < 2) {
    unsigned short* dst = ((m == 0) ? qo : ko) + ((size_t)b * N_ + n) * 64;
    for (int o8 = 0; o8 < 8; ++o8) {
      short8 res;
#pragma unroll
      for (int oo = 0; oo < 8; ++oo) {
        const int o = o8 * 8 + oo;
        float a = bi[o];
        const float* wr = W + o * 64;
#pragma unroll
        for (int c = 0; c < 64; ++c) a = fmaf(xv[c], wr[c], a);
        res[oo] = (short)f2bf(a);
      }
      *(short8*)(dst + o8 * 8) = res;
    }
  } else {
    unsigned short* dst = vto + (size_t)b * C_ * N_ + n;
    for (int o8 = 0; o8 < 8; ++o8) {
#pragma unroll
      for (int oo = 0; oo < 8; ++oo) {
        const int o = o8 * 8 + oo;
        float a = bi[o];
        const float* wr = W + o * 64;
#pragma unroll
        for (int c = 0; c < 64; ++c) a = fmaf(xv[c], wr[c], a);
        dst[(size_t)o * N_] = f2bf(a);
      }
    }
  }
}

// ---------------- Flash attention, swapped 32x32 MFMA, no LDS ----------------
// S^T = K.Q^T via mfma_32x32x16(A=K, B=Q): D[row=k][col=q], col = lane&31.
//   C/D row map: row = (reg&3) + 8*(reg>>2) + 4*hi (verified m74/m101).
//   A/B frag: row(col) = lane&31, k = hi*8 + j (contiguous 8 bf16/lane).
// Softmax over k: in-lane over 16 regs + one __shfl_xor(·,32) (verified primitive).
// PV: out^T = V^T.P^T: A = V^T (vt is [c][n]), B = P^T built with f2bf packs +
//   8x shfl_xor(·,32) + per-lane selects. D[row=c][col=q] matches (m,l) layout.

#define MFMA32(A, B, C) __builtin_amdgcn_mfma_f32_32x32x16_bf16(A, B, C, 0, 0, 0)

#define LOADK(KF, T) { \
  const unsigned short* kr_ = kb + ((size_t)((T) * 32 + q31)) * 64 + hi * 8; \
  KF##0 = *(const short8*)(kr_);      KF##1 = *(const short8*)(kr_ + 16); \
  KF##2 = *(const short8*)(kr_ + 32); KF##3 = *(const short8*)(kr_ + 48); }

#define LOADV(VF, T) { \
  const unsigned short* vr_ = vb + (size_t)q31 * N_ + (T) * 32 + hi * 8; \
  VF##0 = *(const short8*)(vr_);      VF##1 = *(const short8*)(vr_ + 16); \
  VF##2 = *(const short8*)(vr_ + (size_t)32 * N_); \
  VF##3 = *(const short8*)(vr_ + (size_t)32 * N_ + 16); }

#define COMPUTE(KF, VF) do { \
  f32x16 s_ = {0.f,0.f,0.f,0.f,0.f,0.f,0.f,0.f,0.f,0.f,0.f,0.f,0.f,0.f,0.f,0.f}; \
  s_ = MFMA32(KF##0, qf0, s_); s_ = MFMA32(KF##1, qf1, s_); \
  s_ = MFMA32(KF##2, qf2, s_); s_ = MFMA32(KF##3, qf3, s_); \
  float mx = fmaxf(fmaxf(fmaxf(fmaxf(s_[0], s_[1]), fmaxf(s_[2], s_[3])), \
                         fmaxf(fmaxf(s_[4], s_[5]), fmaxf(s_[6], s_[7]))), \
                   fmaxf(fmaxf(fmaxf(s_[8], s_[9]), fmaxf(s_[10], s_[11])), \
                         fmaxf(fmaxf(s_[12], s_[13]), fmaxf(s_[14], s_[15])))); \
  mx = fmaxf(mx, __shfl_xor(mx, 32)) * sc; \
  const float mn_ = fmaxf(m_, mx); \
  const float al_ = __builtin_amdgcn_exp2f(m_ - mn_); /* first iter: exp2(-inf)=0 */ \
  m_ = mn_; l_ *= al_; \
  _Pragma("unroll") \
  for (int r_ = 0; r_ < 16; ++r_) { o0[r_] *= al_; o1[r_] *= al_; } \
  _Pragma("unroll") \
  for (int r_ = 0; r_ < 16; ++r_) s_[r_] = __builtin_amdgcn_exp2f(fmaf(s_[r_], sc, -m_)); \
  float rs = (((s_[0] + s_[1]) + (s_[2] + s_[3])) + ((s_[4] + s_[5]) + (s_[6] + s_[7]))) + \
             (((s_[8] + s_[9]) + (s_[10] + s_[11])) + ((s_[12] + s_[13]) + (s_[14] + s_[15]))); \
  rs += __shfl_xor(rs, 32); \
  l_ += rs; \
  /* pack pairs: at hi=0 lane Axx hold krows (0..7), Bxx (8..15), Cxx (16..23), Dxx (24..31); */ \
  /* at hi=1: +4. B-frag needs dwords: [0,1]=k(hi*8+0..3) [2,3]=k(hi*8+4..7) per 16-k block. */ \
  const int A0 = pk2(s_[0], s_[1]),   A1 = pk2(s_[2], s_[3]); \
  const int Bv0 = pk2(s_[4], s_[5]),  Bv1 = pk2(s_[6], s_[7]); \
  const int C0 = pk2(s_[8], s_[9]),   C1 = pk2(s_[10], s_[11]); \
  const int D0 = pk2(s_[12], s_[13]), D1 = pk2(s_[14], s_[15]); \
  const int xA0 = __shfl_xor(A0, 32),  xA1 = __shfl_xor(A1, 32); \
  const int xB0 = __shfl_xor(Bv0, 32), xB1 = __shfl_xor(Bv1, 32); \
  const int xC0 = __shfl_xor(C0, 32),  xC1 = __shfl_xor(C1, 32); \
  const int xD0 = __shfl_xor(D0, 32),  xD1 = __shfl_xor(D1, 32); \
  const short8 P0 = __builtin_bit_cast(short8, \
      (i32x4){hi ? xB0 : A0, hi ? xB1 : A1, hi ? Bv0 : xA0, hi ? Bv1 : xA1}); \
  const short8 P1 = __builtin_bit_cast(short8, \
      (i32x4){hi ? xD0 : C0, hi ? xD1 : C1, hi ? D0 : xC0, hi ? D1 : xC1}); \
  o0 = MFMA32(VF##0, P0, o0); o0 = MFMA32(VF##1, P1, o0); \
  o1 = MFMA32(VF##2, P0, o1); o1 = MFMA32(VF##3, P1, o1); \
} while (0)

__global__ __launch_bounds__(256, 3) void flash_attn2(
    const unsigned short* __restrict__ q,
    const unsigned short* __restrict__ k,
    const unsigned short* __restrict__ vt,
    float* __restrict__ out,
    float* __restrict__ po, float* __restrict__ pm, float* __restrict__ pl,
    int nsplit, int tiles) {
  const int b = blockIdx.x & 7;        // batch -> XCD pinning (L2 locality)
  const int j = blockIdx.x >> 3;
  const int w = threadIdx.x >> 6;
  const int item = j * 4 + w;          // [0, 128*nsplit)
  const int qb = item & 127;
  const int split = item >> 7;
  const int lane = threadIdx.x & 63;
  const int q31 = lane & 31;
  const int hi = lane >> 5;

  const float sc = 0.18033688011112042f;  // (1/sqrt(64)) * log2(e)

  // Q B-fragments: Q[qb*32 + q31][ks*16 + hi*8 + j]
  const unsigned short* qp = q + ((size_t)b * N_ + qb * 32 + q31) * 64 + hi * 8;
  short8 qf0 = *(const short8*)(qp);
  short8 qf1 = *(const short8*)(qp + 16);
  short8 qf2 = *(const short8*)(qp + 32);
  short8 qf3 = *(const short8*)(qp + 48);

  const unsigned short* kb = k + (size_t)b * N_ * 64;
  const unsigned short* vb = vt + (size_t)b * 64 * N_;

  f32x16 o0 = {0.f,0.f,0.f,0.f,0.f,0.f,0.f,0.f,0.f,0.f,0.f,0.f,0.f,0.f,0.f,0.f};
  f32x16 o1 = o0;
  float m_ = -1e30f, l_ = 0.f;

  short8 kA0, kA1, kA2, kA3, kB0, kB1, kB2, kB3;
  short8 vA0, vA1, vA2, vA3, vB0, vB1, vB2, vB3;

  const int t0 = split * tiles, t1 = t0 + tiles;
  LOADK(kA, t0);
  for (int t = t0; t < t1; t += 2) {
    LOADV(vA, t);
    LOADK(kB, t + 1);
    COMPUTE(kA, vA);
    LOADV(vB, t + 1);
    { const int tn = (t + 2 < t1) ? t + 2 : t0; LOADK(kA, tn); }  // prefetch (clamped)
    COMPUTE(kB, vB);
  }

  const int n_ = qb * 32 + q31;
  if (nsplit == 1) {
    const float inv = 1.f / l_;
    float* ob = out + (size_t)b * 64 * N_ + n_;
#pragma unroll
    for (int r_ = 0; r_ < 16; ++r_) {
      const int cl = (r_ & 3) + 8 * (r_ >> 2) + 4 * hi;
      ob[(size_t)cl * N_] = o0[r_] * inv;
      ob[(size_t)(cl + 32) * N_] = o1[r_] * inv;
    }
  } else {
    // partials: po[split][b][c][n] unnormalized; pm/pl[split][b][n]
    float* pr = po + ((size_t)(split * B_ + b) * 64) * N_ + n_;
#pragma unroll
    for (int r_ = 0; r_ < 16; ++r_) {
      const int cl = (r_ & 3) + 8 * (r_ >> 2) + 4 * hi;
      pr[(size_t)cl * N_] = o0[r_];
      pr[(size_t)(cl + 32) * N_] = o1[r_];
    }
    if (hi == 0) {
      const size_t ix = (size_t)(split * B_ + b) * N_ + n_;
      pm[ix] = m_;
      pl[ix] = l_;
    }
  }
}

// ---------------- Combine partials ----------------
template <int NS>
__global__ __launch_bounds__(256) void combine_k(
    const float* __restrict__ po, const float* __restrict__ pm,
    const float* __restrict__ pl, float* __restrict__ out) {
  const int b = blockIdx.y;
  const int n4 = (blockIdx.x * 256 + threadIdx.x) * 4;
  const size_t sb = (size_t)B_ * N_;

  f32x4 pmv[NS], plv[NS], al[NS];
  f32x4 mm = {-1e30f, -1e30f, -1e30f, -1e30f};
#pragma unroll
  for (int s = 0; s < NS; ++s) {
    pmv[s] = *(const f32x4*)(pm + s * sb + (size_t)b * N_ + n4);
    plv[s] = *(const f32x4*)(pl + s * sb + (size_t)b * N_ + n4);
#pragma unroll
    for (int e = 0; e < 4; ++e) mm[e] = fmaxf(mm[e], pmv[s][e]);
  }
  f32x4 l = {0.f, 0.f, 0.f, 0.f};
#pragma unroll
  for (int s = 0; s < NS; ++s) {
#pragma unroll
    for (int e = 0; e < 4; ++e) {
      al[s][e] = __builtin_amdgcn_exp2f(pmv[s][e] - mm[e]);
      l[e] += al[s][e] * plv[s][e];
    }
  }
  f32x4 inv;
#pragma unroll
  for (int e = 0; e < 4; ++e) inv[e] = 1.f / l[e];

  float* ob = out + (size_t)b * 64 * N_ + n4;
  for (int c = 0; c < 64; ++c) {
    f32x4 acc = {0.f, 0.f, 0.f, 0.f};
#pragma unroll
    for (int s = 0; s < NS; ++s) {
      const f32x4 pv = *(const f32x4*)(po + ((size_t)(s * B_ + b) * 64 + c) * N_ + n4);
#pragma unroll
      for (int e = 0; e < 4; ++e) acc[e] += al[s][e] * pv[e];
    }
    f32x4 res;
#pragma unroll
    for (int e = 0; e < 4; ++e) res[e] = acc[e] * inv[e];
    *(f32x4*)(ob + (size_t)c * N_) = res;
  }
}

extern "C" void kernel_launch(void* const* d_in, const int* in_sizes, int n_in,
                              void* d_out, int out_size, void* d_ws, size_t ws_size,
                              hipStream_t stream) {
  const float* x  = (const float*)d_in[0];
  const float* Wq = (const float*)d_in[1];
  const float* bq = (const float*)d_in[2];
  const float* Wk = (const float*)d_in[3];
  const float* bk = (const float*)d_in[4];
  const float* Wv = (const float*)d_in[5];
  const float* bv = (const float*)d_in[6];
  float* out = (float*)d_out;

  unsigned short* qws = (unsigned short*)d_ws;          // [B][N][64] bf16
  unsigned short* kws = qws + (size_t)B_ * N_ * 64;     // [B][N][64] bf16
  unsigned short* vws = kws + (size_t)B_ * N_ * 64;     // [B][64][N] bf16 (transposed)

  const size_t qkv_bytes = (size_t)3 * B_ * N_ * 64 * 2;                          // 12 MB
  const size_t per_split = (size_t)B_ * N_ * 64 * 4 + (size_t)2 * B_ * N_ * 4;    // 8.25 MB

  int S = 1;
  if (ws_size >= qkv_bytes + 8 * per_split) S = 8;
  else if (ws_size >= qkv_bytes + 4 * per_split) S = 4;
  else if (ws_size >= qkv_bytes + 2 * per_split) S = 2;

  float* po = (float*)((char*)d_ws + qkv_bytes);        // [S][B][64][N]
  float* pm = po + (size_t)S * B_ * N_ * 64;            // [S][B][N]
  float* pl = pm + (size_t)S * B_ * N_;                 // [S][B][N]

  dim3 gp(N_ / 256, 3, B_);
  qkv_proj<<<gp, 256, 0, stream>>>(x, Wq, bq, Wk, bk, Wv, bv, qws, kws, vws);

  flash_attn2<<<256 * S, 256, 0, stream>>>(qws, kws, vws, out, po, pm, pl, S, 128 / S);

  if (S == 8)      combine_k<8><<<dim3(N_ / 1024, B_), 256, 0, stream>>>(po, pm, pl, out);
  else if (S == 4) combine_k<4><<<dim3(N_ / 1024, B_), 256, 0, stream>>>(po, pm, pl, out);
  else if (S == 2) combine_k<2><<<dim3(N_ / 1024, B_), 256, 0, stream>>>(po, pm, pl, out);
}

// Round 7
// 166.110 us; speedup vs baseline: 2.0409x; 2.0409x over previous
//
#include <hip/hip_runtime.h>
#include <stdint.h>

typedef __attribute__((ext_vector_type(8))) short short8;
typedef __attribute__((ext_vector_type(4))) float f32x4;
typedef __attribute__((ext_vector_type(16))) float f32x16;
typedef __attribute__((ext_vector_type(4))) int i32x4;

#define B_ 8
#define C_ 64
#define N_ 4096

__device__ __forceinline__ unsigned short f2bf(float f) {
  unsigned int u = __float_as_uint(f);
  u = (u + 0x7fffu + ((u >> 16) & 1u)) >> 16;
  return (unsigned short)u;
}
__device__ __forceinline__ int pk2(float lo, float hi2) {
  return (int)((unsigned)f2bf(lo) | ((unsigned)f2bf(hi2) << 16));
}

// NOTE (session journal): v_permlane32_swap_b32-based P assembly failed twice
// (rounds 5/6) with orientation-dependent wrong results; its register-file
// semantics remain HW-unverified in this session. All cross-half exchange
// below uses __shfl_xor(.,32) (ds_bpermute) — bit-verified in rounds 1/3/4.

// ---------------- QKV projection: o8 split into grid for parallelism ----------------
// Math identical to round-1-verified version; only thread mapping changed.
__global__ __launch_bounds__(256) void qkv_proj(
    const float* __restrict__ x,
    const float* __restrict__ Wq, const float* __restrict__ bq,
    const float* __restrict__ Wk, const float* __restrict__ bk,
    const float* __restrict__ Wv, const float* __restrict__ bv,
    unsigned short* __restrict__ qo, unsigned short* __restrict__ ko,
    unsigned short* __restrict__ vto) {
  const int n = blockIdx.x * 256 + threadIdx.x;
  const int m = blockIdx.y >> 3;   // 0=q, 1=k, 2=v(transposed)
  const int o8 = blockIdx.y & 7;   // output group of 8
  const int b = blockIdx.z;
  const float* W = (m == 0) ? Wq : (m == 1) ? Wk : Wv;
  const float* bi = (m == 0) ? bq : (m == 1) ? bk : bv;

  float xv[64];
  const float* xp = x + (size_t)b * C_ * N_ + n;
#pragma unroll
  for (int c = 0; c < 64; ++c) xv[c] = xp[(size_t)c * N_];

  float acc[8];
#pragma unroll
  for (int oo = 0; oo < 8; ++oo) {
    const int o = o8 * 8 + oo;
    float a = bi[o];
    const float* wr = W + o * 64;  // wave-uniform -> scalar loads
#pragma unroll
    for (int c = 0; c < 64; ++c) a = fmaf(xv[c], wr[c], a);
    acc[oo] = a;
  }

  if (m < 2) {
    unsigned short* dst = ((m == 0) ? qo : ko) + ((size_t)b * N_ + n) * 64 + o8 * 8;
    short8 res;
#pragma unroll
    for (int oo = 0; oo < 8; ++oo) res[oo] = (short)f2bf(acc[oo]);
    *(short8*)dst = res;
  } else {
    unsigned short* dst = vto + (size_t)b * C_ * N_ + n;
#pragma unroll
    for (int oo = 0; oo < 8; ++oo)
      dst[(size_t)(o8 * 8 + oo) * N_] = f2bf(acc[oo]);  // coalesced across lanes
  }
}

// ---------------- Flash attention: VERBATIM round-4 verified kernel ----------------
// S^T = K.Q^T via mfma_32x32x16(A=K, B=Q): D[row=k][col=q], col = lane&31.
//   C/D row map: row = (reg&3) + 8*(reg>>2) + 4*hi (m74/m101).
//   A/B frag: row(col) = lane&31, k = hi*8 + j (contiguous 8 bf16/lane).
// Softmax over k: in-lane over 16 regs + one __shfl_xor(.,32).
// PV: out^T = V^T.P^T: A = V^T (vt is [c][n]), B = P^T via f2bf packs +
//   8x shfl_xor(.,32) + per-lane selects. D[row=c][col=q] matches (m,l) layout.

#define MFMA32(A, B, C) __builtin_amdgcn_mfma_f32_32x32x16_bf16(A, B, C, 0, 0, 0)

#define LOADK(KF, T) { \
  const unsigned short* kr_ = kb + ((size_t)((T) * 32 + q31)) * 64 + hi * 8; \
  KF##0 = *(const short8*)(kr_);      KF##1 = *(const short8*)(kr_ + 16); \
  KF##2 = *(const short8*)(kr_ + 32); KF##3 = *(const short8*)(kr_ + 48); }

#define LOADV(VF, T) { \
  const unsigned short* vr_ = vb + (size_t)q31 * N_ + (T) * 32 + hi * 8; \
  VF##0 = *(const short8*)(vr_);      VF##1 = *(const short8*)(vr_ + 16); \
  VF##2 = *(const short8*)(vr_ + (size_t)32 * N_); \
  VF##3 = *(const short8*)(vr_ + (size_t)32 * N_ + 16); }

#define COMPUTE(KF, VF) do { \
  f32x16 s_ = {0.f,0.f,0.f,0.f,0.f,0.f,0.f,0.f,0.f,0.f,0.f,0.f,0.f,0.f,0.f,0.f}; \
  s_ = MFMA32(KF##0, qf0, s_); s_ = MFMA32(KF##1, qf1, s_); \
  s_ = MFMA32(KF##2, qf2, s_); s_ = MFMA32(KF##3, qf3, s_); \
  float mx = fmaxf(fmaxf(fmaxf(fmaxf(s_[0], s_[1]), fmaxf(s_[2], s_[3])), \
                         fmaxf(fmaxf(s_[4], s_[5]), fmaxf(s_[6], s_[7]))), \
                   fmaxf(fmaxf(fmaxf(s_[8], s_[9]), fmaxf(s_[10], s_[11])), \
                         fmaxf(fmaxf(s_[12], s_[13]), fmaxf(s_[14], s_[15])))); \
  mx = fmaxf(mx, __shfl_xor(mx, 32)) * sc; \
  const float mn_ = fmaxf(m_, mx); \
  const float al_ = __builtin_amdgcn_exp2f(m_ - mn_); /* first iter: exp2(-inf)=0 */ \
  m_ = mn_; l_ *= al_; \
  _Pragma("unroll") \
  for (int r_ = 0; r_ < 16; ++r_) { o0[r_] *= al_; o1[r_] *= al_; } \
  _Pragma("unroll") \
  for (int r_ = 0; r_ < 16; ++r_) s_[r_] = __builtin_amdgcn_exp2f(fmaf(s_[r_], sc, -m_)); \
  float rs = (((s_[0] + s_[1]) + (s_[2] + s_[3])) + ((s_[4] + s_[5]) + (s_[6] + s_[7]))) + \
             (((s_[8] + s_[9]) + (s_[10] + s_[11])) + ((s_[12] + s_[13]) + (s_[14] + s_[15]))); \
  rs += __shfl_xor(rs, 32); \
  l_ += rs; \
  const int A0 = pk2(s_[0], s_[1]),   A1 = pk2(s_[2], s_[3]); \
  const int Bv0 = pk2(s_[4], s_[5]),  Bv1 = pk2(s_[6], s_[7]); \
  const int C0 = pk2(s_[8], s_[9]),   C1 = pk2(s_[10], s_[11]); \
  const int D0 = pk2(s_[12], s_[13]), D1 = pk2(s_[14], s_[15]); \
  const int xA0 = __shfl_xor(A0, 32),  xA1 = __shfl_xor(A1, 32); \
  const int xB0 = __shfl_xor(Bv0, 32), xB1 = __shfl_xor(Bv1, 32); \
  const int xC0 = __shfl_xor(C0, 32),  xC1 = __shfl_xor(C1, 32); \
  const int xD0 = __shfl_xor(D0, 32),  xD1 = __shfl_xor(D1, 32); \
  const short8 P0 = __builtin_bit_cast(short8, \
      (i32x4){hi ? xB0 : A0, hi ? xB1 : A1, hi ? Bv0 : xA0, hi ? Bv1 : xA1}); \
  const short8 P1 = __builtin_bit_cast(short8, \
      (i32x4){hi ? xD0 : C0, hi ? xD1 : C1, hi ? D0 : xC0, hi ? D1 : xC1}); \
  o0 = MFMA32(VF##0, P0, o0); o0 = MFMA32(VF##1, P1, o0); \
  o1 = MFMA32(VF##2, P0, o1); o1 = MFMA32(VF##3, P1, o1); \
} while (0)

__global__ __launch_bounds__(256, 3) void flash_attn2(
    const unsigned short* __restrict__ q,
    const unsigned short* __restrict__ k,
    const unsigned short* __restrict__ vt,
    float* __restrict__ out,
    float* __restrict__ po, float* __restrict__ pm, float* __restrict__ pl,
    int nsplit, int tiles) {
  const int b = blockIdx.x & 7;        // batch -> XCD pinning (L2 locality)
  const int j = blockIdx.x >> 3;
  const int w = threadIdx.x >> 6;
  const int item = j * 4 + w;          // [0, 128*nsplit)
  const int qb = item & 127;
  const int split = item >> 7;
  const int lane = threadIdx.x & 63;
  const int q31 = lane & 31;
  const int hi = lane >> 5;

  const float sc = 0.18033688011112042f;  // (1/sqrt(64)) * log2(e)

  // Q B-fragments: Q[qb*32 + q31][ks*16 + hi*8 + j]
  const unsigned short* qp = q + ((size_t)b * N_ + qb * 32 + q31) * 64 + hi * 8;
  short8 qf0 = *(const short8*)(qp);
  short8 qf1 = *(const short8*)(qp + 16);
  short8 qf2 = *(const short8*)(qp + 32);
  short8 qf3 = *(const short8*)(qp + 48);

  const unsigned short* kb = k + (size_t)b * N_ * 64;
  const unsigned short* vb = vt + (size_t)b * 64 * N_;

  f32x16 o0 = {0.f,0.f,0.f,0.f,0.f,0.f,0.f,0.f,0.f,0.f,0.f,0.f,0.f,0.f,0.f,0.f};
  f32x16 o1 = o0;
  float m_ = -1e30f, l_ = 0.f;

  short8 kA0, kA1, kA2, kA3, kB0, kB1, kB2, kB3;
  short8 vA0, vA1, vA2, vA3, vB0, vB1, vB2, vB3;

  const int t0 = split * tiles, t1 = t0 + tiles;
  LOADK(kA, t0);
  for (int t = t0; t < t1; t += 2) {
    LOADV(vA, t);
    LOADK(kB, t + 1);
    COMPUTE(kA, vA);
    LOADV(vB, t + 1);
    { const int tn = (t + 2 < t1) ? t + 2 : t0; LOADK(kA, tn); }  // prefetch (clamped)
    COMPUTE(kB, vB);
  }

  const int n_ = qb * 32 + q31;
  if (nsplit == 1) {
    const float inv = 1.f / l_;
    float* ob = out + (size_t)b * 64 * N_ + n_;
#pragma unroll
    for (int r_ = 0; r_ < 16; ++r_) {
      const int cl = (r_ & 3) + 8 * (r_ >> 2) + 4 * hi;
      ob[(size_t)cl * N_] = o0[r_] * inv;
      ob[(size_t)(cl + 32) * N_] = o1[r_] * inv;
    }
  } else {
    // partials: po[split][b][c][n] unnormalized; pm/pl[split][b][n]
    float* pr = po + ((size_t)(split * B_ + b) * 64) * N_ + n_;
#pragma unroll
    for (int r_ = 0; r_ < 16; ++r_) {
      const int cl = (r_ & 3) + 8 * (r_ >> 2) + 4 * hi;
      pr[(size_t)cl * N_] = o0[r_];
      pr[(size_t)(cl + 32) * N_] = o1[r_];
    }
    if (hi == 0) {
      const size_t ix = (size_t)(split * B_ + b) * N_ + n_;
      pm[ix] = m_;
      pl[ix] = l_;
    }
  }
}

// ---------------- Combine partials: thread = one n, 8 c's ----------------
// Math identical to round-4-verified combine; only thread mapping changed
// (1024 blocks instead of 32 -> fixes the 1.1%-occupancy bottleneck).
template <int NS>
__global__ __launch_bounds__(256) void combine_k(
    const float* __restrict__ po, const float* __restrict__ pm,
    const float* __restrict__ pl, float* __restrict__ out) {
  const int n = blockIdx.x * 256 + threadIdx.x;  // grid.x = N_/256
  const int c0 = blockIdx.y * 8;                 // grid.y = 8
  const int b = blockIdx.z;
  const size_t sb = (size_t)B_ * N_;

  float mv[NS], al[NS];
  float mm = -1e30f;
#pragma unroll
  for (int s = 0; s < NS; ++s) {
    mv[s] = pm[s * sb + (size_t)b * N_ + n];
    mm = fmaxf(mm, mv[s]);
  }
  float l = 0.f;
#pragma unroll
  for (int s = 0; s < NS; ++s) {
    al[s] = __builtin_amdgcn_exp2f(mv[s] - mm);
    l += al[s] * pl[s * sb + (size_t)b * N_ + n];
  }
  const float inv = 1.f / l;

#pragma unroll
  for (int cc = 0; cc < 8; ++cc) {
    float acc = 0.f;
#pragma unroll
    for (int s = 0; s < NS; ++s)
      acc += al[s] * po[((size_t)(s * B_ + b) * 64 + c0 + cc) * N_ + n];
    out[((size_t)b * 64 + c0 + cc) * N_ + n] = acc * inv;
  }
}

extern "C" void kernel_launch(void* const* d_in, const int* in_sizes, int n_in,
                              void* d_out, int out_size, void* d_ws, size_t ws_size,
                              hipStream_t stream) {
  const float* x  = (const float*)d_in[0];
  const float* Wq = (const float*)d_in[1];
  const float* bq = (const float*)d_in[2];
  const float* Wk = (const float*)d_in[3];
  const float* bk = (const float*)d_in[4];
  const float* Wv = (const float*)d_in[5];
  const float* bv = (const float*)d_in[6];
  float* out = (float*)d_out;

  unsigned short* qws = (unsigned short*)d_ws;          // [B][N][64] bf16
  unsigned short* kws = qws + (size_t)B_ * N_ * 64;     // [B][N][64] bf16
  unsigned short* vws = kws + (size_t)B_ * N_ * 64;     // [B][64][N] bf16 (transposed)

  const size_t qkv_bytes = (size_t)3 * B_ * N_ * 64 * 2;                          // 12 MB
  const size_t per_split = (size_t)B_ * N_ * 64 * 4 + (size_t)2 * B_ * N_ * 4;    // 8.25 MB

  int S = 1;
  if (ws_size >= qkv_bytes + 8 * per_split) S = 8;
  else if (ws_size >= qkv_bytes + 4 * per_split) S = 4;
  else if (ws_size >= qkv_bytes + 2 * per_split) S = 2;

  float* po = (float*)((char*)d_ws + qkv_bytes);        // [S][B][64][N]
  float* pm = po + (size_t)S * B_ * N_ * 64;            // [S][B][N]
  float* pl = pm + (size_t)S * B_ * N_;                 // [S][B][N]

  dim3 gp(N_ / 256, 24, B_);
  qkv_proj<<<gp, 256, 0, stream>>>(x, Wq, bq, Wk, bk, Wv, bv, qws, kws, vws);

  flash_attn2<<<256 * S, 256, 0, stream>>>(qws, kws, vws, out, po, pm, pl, S, 128 / S);

  if (S == 8)      combine_k<8><<<dim3(N_ / 256, 8, B_), 256, 0, stream>>>(po, pm, pl, out);
  else if (S == 4) combine_k<4><<<dim3(N_ / 256, 8, B_), 256, 0, stream>>>(po, pm, pl, out);
  else if (S == 2) combine_k<2><<<dim3(N_ / 256, 8, B_), 256, 0, stream>>>(po, pm, pl, out);
}